// Round 13
// baseline (223.988 us; speedup 1.0000x reference)
//
#include <hip/hip_runtime.h>

typedef __bf16 bf16x8 __attribute__((ext_vector_type(8)));
typedef float f32x4 __attribute__((ext_vector_type(4)));

#define DIM 1024
#define NSEQ 2048

// async 16B global -> LDS DMA (lane-linear: wave-uniform LDS base + lane*16)
#define GL2LDS(g, l) __builtin_amdgcn_global_load_lds( \
    (const __attribute__((address_space(1))) void*)(g), \
    (__attribute__((address_space(3))) void*)(l), 16, 0, 0)

// ---------------- fp32 -> bf16 weight conversion ----------------
__global__ __launch_bounds__(256) void cvt_kernel(const float* __restrict__ s,
                                                  __bf16* __restrict__ d) {
    int i = (blockIdx.x * 256 + threadIdx.x) * 4;
    float4 f = *(const float4*)(s + i);
    union { uint2 u; __bf16 h[4]; } p;
    p.h[0] = (__bf16)f.x; p.h[1] = (__bf16)f.y;
    p.h[2] = (__bf16)f.z; p.h[3] = (__bf16)f.w;
    *(uint2*)(d + i) = p.u;
}

// ---------------- zero the 8 per-XCD work-queue counters ----------------
__global__ void init_kernel(int* c) { c[threadIdx.x] = 0; }

// ---------------- RMSNorm: fp32 in, bf16 out ----------------
__global__ __launch_bounds__(256) void rmsnorm_kernel(const float* __restrict__ x,
                                                      const float* __restrict__ g,
                                                      __bf16* __restrict__ o) {
    int row = blockIdx.x;
    int t = threadIdx.x;
    float4 xv = ((const float4*)(x + (size_t)row * DIM))[t];
    float ss = xv.x*xv.x + xv.y*xv.y + xv.z*xv.z + xv.w*xv.w;
    #pragma unroll
    for (int off = 32; off; off >>= 1) ss += __shfl_xor(ss, off, 64);
    __shared__ float red[4];
    if ((t & 63) == 0) red[t >> 6] = ss;
    __syncthreads();
    ss = red[0] + red[1] + red[2] + red[3];
    float r = rsqrtf(ss * (1.0f / 1024.0f) + 1.1920929e-07f);
    float4 gv = ((const float4*)g)[t];
    union { uint2 u; __bf16 h[4]; } p;
    p.h[0] = (__bf16)(xv.x * r * gv.x);
    p.h[1] = (__bf16)(xv.y * r * gv.y);
    p.h[2] = (__bf16)(xv.z * r * gv.z);
    p.h[3] = (__bf16)(xv.w * r * gv.w);
    *(uint2*)(o + (size_t)row * DIM + t * 4) = p.u;
}

// ---------------- RoPE in-place on (4096 x 1024) bf16, heads of 64 ----------------
__global__ __launch_bounds__(256) void rope_kernel(__bf16* __restrict__ x) {
    int gid = blockIdx.x * 256 + threadIdx.x;   // one pair per thread
    int row = gid >> 9;          // 512 pairs per row
    int pr = gid & 511;
    int pos = row & (NSEQ - 1);
    int dp = pr & 31;            // pair index within head
    float inv = __expf(-(float)dp * (9.210340371976184f / 32.0f)); // 10000^(-2dp/64)
    float ang = (float)pos * inv;
    float sn, cs;
    sincosf(ang, &sn, &cs);
    size_t off = (size_t)row * DIM + pr * 2;
    union { unsigned int u; __bf16 h[2]; } p;
    p.u = *(const unsigned int*)(x + off);
    float x1 = (float)p.h[0], x2 = (float)p.h[1];
    p.h[0] = (__bf16)(x1 * cs - x2 * sn);
    p.h[1] = (__bf16)(x2 * cs + x1 * sn);
    *(unsigned int*)(x + off) = p.u;
}

// ---------------- GEMM body, 128x64 tile: C[i,j]=scale*sum_k A[mb*128+i,k]B[nb*64+j,k]
// BK=32, 12 KB LDS (unpadded stride-32) via global_load_lds, 2 barriers/iter.
// 4 waves in 2x2, each 64x32 (8 MFMA/iter) — thin tiles, deep grid (6 blocks/CU).
template <typename CT>
__device__ __forceinline__ void gemm_body64(const __bf16* __restrict__ A,
                                            const __bf16* __restrict__ B,
                                            CT* __restrict__ C,
                                            int mb, int nb, int ldc, float scale,
                                            __bf16* As, __bf16* Bs) {
    int t = threadIdx.x;
    int w = t >> 6, l = t & 63;
    int wm = (w >> 1) * 64, wn = (w & 1) * 32;   // wave 2x2 grid, each 64x32
    int lrow = l & 15, lq = l >> 4;
    f32x4 acc[4][2] = {};

    // DMA geometry: lane l covers row w*16 + (l>>2), col block (l&3)*8.
    int srow = w * 16 + (l >> 2);
    int sc8 = (l & 3) * 8;
    const __bf16* gA = A + (size_t)(mb * 128 + srow) * 1024 + sc8;
    const __bf16* gB = B + (size_t)(nb * 64 + srow) * 1024 + sc8;
    __bf16* lA = As + (w * 64) * 8;              // lane-linear slots; + c*256*8
    __bf16* lB = Bs + (w * 64) * 8;

    for (int kt = 0; kt < 32; ++kt) {
        int k0 = kt * 32;
        GL2LDS(gA + k0, lA);                     // A rows 0-63
        GL2LDS(gA + k0 + (size_t)64 * 1024, lA + 256 * 8);   // A rows 64-127
        GL2LDS(gB + k0, lB);                     // B rows 0-63
        __syncthreads();    // drains DMA, publishes tile
        bf16x8 af[4], bfr[2];
        #pragma unroll
        for (int i = 0; i < 4; ++i)
            af[i] = *(const bf16x8*)&As[(wm + i * 16 + lrow) * 32 + lq * 8];
        #pragma unroll
        for (int j = 0; j < 2; ++j)
            bfr[j] = *(const bf16x8*)&Bs[(wn + j * 16 + lrow) * 32 + lq * 8];
        #pragma unroll
        for (int i = 0; i < 4; ++i)
            #pragma unroll
            for (int j = 0; j < 2; ++j)
                acc[i][j] = __builtin_amdgcn_mfma_f32_16x16x32_bf16(
                    af[i], bfr[j], acc[i][j], 0, 0, 0);
        __syncthreads();
    }
    #pragma unroll
    for (int i = 0; i < 4; ++i)
        #pragma unroll
        for (int j = 0; j < 2; ++j)
            #pragma unroll
            for (int r = 0; r < 4; ++r) {
                int row = mb * 128 + wm + i * 16 + lq * 4 + r;   // C-layout
                int col = nb * 64 + wn + j * 16 + lrow;
                C[(size_t)row * ldc + col] = (CT)(acc[i][j][r] * scale);
            }
}

// Fused QKV projections: grid (32, 16, 3) -> 1536 blocks = 6/CU.
// z=0: Q (scale folds 1/8 AND log2e for base-2 softmax), z=1: K, z=2: V^T.
__global__ __launch_bounds__(256) void qkv_kernel(const __bf16* __restrict__ x,
                                                  const __bf16* __restrict__ wq,
                                                  const __bf16* __restrict__ wk,
                                                  const __bf16* __restrict__ wv,
                                                  __bf16* __restrict__ qb,
                                                  __bf16* __restrict__ kb,
                                                  __bf16* __restrict__ vtb) {
    __shared__ __bf16 As[128 * 32];
    __shared__ __bf16 Bs[64 * 32];
    int bm = blockIdx.x, bn = blockIdx.y, z = blockIdx.z;
    if (z == 0)      gemm_body64<__bf16>(x, wq, qb, bm, bn, 1024, 0.18033688f, As, Bs);
    else if (z == 1) gemm_body64<__bf16>(x, wk, kb, bm, bn, 1024, 1.0f, As, Bs);
    else {           // V^T: C'[j,i] = sum_k wv[j,k] x[i,k]; M-tiles 8, N-tiles 64
        int mb = bn >> 1;
        int nb = bm * 2 + (bn & 1);
        gemm_body64<__bf16>(wv, x, vtb, mb, nb, 4096, 1.0f, As, Bs);
    }
}

// Output projection: grid (32,16) = 512 blocks = 2/CU, fp32 store.
__global__ __launch_bounds__(256) void wo_kernel(const __bf16* __restrict__ A,
                                                 const __bf16* __restrict__ B,
                                                 float* __restrict__ C) {
    __shared__ __bf16 As[128 * 32];
    __shared__ __bf16 Bs[64 * 32];
    gemm_body64<float>(A, B, C, blockIdx.x, blockIdx.y, 1024, 1.0f, As, Bs);
}

// ---------------- Causal flash attention: persistent blocks + per-XCD queues ----
// Scores arrive pre-scaled by log2e -> softmax uses exp2f (bare v_exp_f32).
__global__ __launch_bounds__(256, 2) void attn_kernel(const __bf16* __restrict__ q,
                                                      const __bf16* __restrict__ kk,
                                                      const __bf16* __restrict__ vt,
                                                      __bf16* __restrict__ o,
                                                      int* __restrict__ counters) {
    int xcd = blockIdx.x & 7;            // dispatch round-robins over XCDs
    int t = threadIdx.x;
    int w = t >> 6, l = t & 63;
    int lrow = l & 15, lq = l >> 4;
    int row0 = t >> 3;
    int c8 = (t & 7) * 8;

    __shared__ __bf16 Kt[2][64 * 72];    // [key][d], stride 72
    __shared__ __bf16 Vs[2][64 * 72];    // [d][key], stride 72 (from vt)
    __shared__ __bf16 Ps[4 * 16 * 72];   // per-wave P^T strip [qrow][key]
    __shared__ int s_item;
    __bf16* pw = &Ps[w * 16 * 72];

    for (;;) {
        if (t == 0) s_item = atomicAdd(&counters[xcd], 1);
        __syncthreads();                 // broadcast item; also fences LDS reuse
        int item = s_item;
        if (item >= 128) break;
        int qt = 31 - (item >> 2);       // long q-tiles first (LPT)
        int bh = xcd * 4 + (item & 3);   // 4 (b,h) pairs resident per XCD
        int h = bh & 15;
        int b = bh >> 4;
        int rowbase = b * NSEQ;

        const __bf16* kbase = kk + (size_t)rowbase * DIM + h * 64;
        const __bf16* vbase = vt + (size_t)(h * 64) * 4096 + b * 2048;

        // Q as B-fragment: B[n=qrow=l&15][k=d=(l>>4)*8+j]
        const __bf16* qp = q + (size_t)(rowbase + qt * 64 + w * 16 + lrow) * DIM + h * 64;
        bf16x8 qb0 = *(const bf16x8*)(qp + lq * 8);
        bf16x8 qb1 = *(const bf16x8*)(qp + 32 + lq * 8);

        f32x4 oacc[4] = {};              // O^T: [d-chunk], col = qrow
        float m_r = -1e30f, l_r = 0.0f;  // per-lane scalars (qrow = lrow)

        // stage tile 0 into buffer 0 (explicit named regs -> no scratch)
        uint4 kr0, kr1, vr0, vr1;
        kr0 = *(const uint4*)(kbase + (size_t)row0 * DIM + c8);
        kr1 = *(const uint4*)(kbase + (size_t)(row0 + 32) * DIM + c8);
        vr0 = *(const uint4*)(vbase + (size_t)row0 * 4096 + c8);
        vr1 = *(const uint4*)(vbase + (size_t)(row0 + 32) * 4096 + c8);
        *(uint4*)&Kt[0][row0 * 72 + c8] = kr0;
        *(uint4*)&Kt[0][(row0 + 32) * 72 + c8] = kr1;
        *(uint4*)&Vs[0][row0 * 72 + c8] = vr0;
        *(uint4*)&Vs[0][(row0 + 32) * 72 + c8] = vr1;
        __syncthreads();

        for (int jt = 0; jt <= qt; ++jt) {
            int cur = jt & 1;
            if (jt < qt) {               // register prefetch of next K/V tile
                int j0 = (jt + 1) * 64;
                kr0 = *(const uint4*)(kbase + (size_t)(j0 + row0) * DIM + c8);
                kr1 = *(const uint4*)(kbase + (size_t)(j0 + row0 + 32) * DIM + c8);
                vr0 = *(const uint4*)(vbase + (size_t)row0 * 4096 + j0 + c8);
                vr1 = *(const uint4*)(vbase + (size_t)(row0 + 32) * 4096 + j0 + c8);
            }
            // S^T strip (64 keys x 16 qrows): A = K[m=key][k=d], B = Q
            f32x4 st[4];
            #pragma unroll
            for (int ct = 0; ct < 4; ++ct) {
                f32x4 z = {};
                bf16x8 ka0 = *(const bf16x8*)&Kt[cur][(ct * 16 + lrow) * 72 + lq * 8];
                bf16x8 ka1 = *(const bf16x8*)&Kt[cur][(ct * 16 + lrow) * 72 + 32 + lq * 8];
                z = __builtin_amdgcn_mfma_f32_16x16x32_bf16(ka0, qb0, z, 0, 0, 0);
                z = __builtin_amdgcn_mfma_f32_16x16x32_bf16(ka1, qb1, z, 0, 0, 0);
                st[ct] = z;              // key = ct*16+lq*4+r, qrow(local) = lrow
            }
            if (jt == qt) {              // causal mask on diagonal tile
                int qr = w * 16 + lrow;
                #pragma unroll
                for (int ct = 0; ct < 4; ++ct)
                    #pragma unroll
                    for (int r = 0; r < 4; ++r)
                        if (ct * 16 + lq * 4 + r > qr) st[ct][r] = -3.0e38f;
            }
            // per-lane online softmax in base-2 domain (2 shuffles)
            float mx = st[0][0];
            #pragma unroll
            for (int ct = 0; ct < 4; ++ct)
                #pragma unroll
                for (int r = 0; r < 4; ++r) mx = fmaxf(mx, st[ct][r]);
            mx = fmaxf(mx, __shfl_xor(mx, 16, 64));
            mx = fmaxf(mx, __shfl_xor(mx, 32, 64));
            float mnew = fmaxf(m_r, mx);
            float alpha = exp2f(m_r - mnew);
            float ps = 0.0f;
            #pragma unroll
            for (int ct = 0; ct < 4; ++ct)
                #pragma unroll
                for (int r = 0; r < 4; ++r) {
                    float p = exp2f(st[ct][r] - mnew);
                    st[ct][r] = p;
                    ps += p;
                }
            ps += __shfl_xor(ps, 16, 64);
            ps += __shfl_xor(ps, 32, 64);
            l_r = l_r * alpha + ps;
            m_r = mnew;

            // P^T -> per-wave strip (same-wave reuse, no barrier)
            #pragma unroll
            for (int ct = 0; ct < 4; ++ct) {
                union { uint2 u; __bf16 h4[4]; } pk;
                #pragma unroll
                for (int r = 0; r < 4; ++r) pk.h4[r] = (__bf16)st[ct][r];
                *(uint2*)&pw[lrow * 72 + ct * 16 + lq * 4] = pk.u;
            }
            #pragma unroll
            for (int ct = 0; ct < 4; ++ct)
                #pragma unroll
                for (int r = 0; r < 4; ++r) oacc[ct][r] *= alpha;
            // O^T += V^T * P^T
            bf16x8 pb0 = *(const bf16x8*)&pw[lrow * 72 + lq * 8];
            bf16x8 pb1 = *(const bf16x8*)&pw[lrow * 72 + 32 + lq * 8];
            #pragma unroll
            for (int ct = 0; ct < 4; ++ct) {
                bf16x8 va0 = *(const bf16x8*)&Vs[cur][(ct * 16 + lrow) * 72 + lq * 8];
                bf16x8 va1 = *(const bf16x8*)&Vs[cur][(ct * 16 + lrow) * 72 + 32 + lq * 8];
                oacc[ct] = __builtin_amdgcn_mfma_f32_16x16x32_bf16(va0, pb0, oacc[ct], 0, 0, 0);
                oacc[ct] = __builtin_amdgcn_mfma_f32_16x16x32_bf16(va1, pb1, oacc[ct], 0, 0, 0);
            }
            // store prefetched tile into ALTERNATE buffer (readers use `cur`)
            if (jt < qt) {
                *(uint4*)&Kt[cur ^ 1][row0 * 72 + c8] = kr0;
                *(uint4*)&Kt[cur ^ 1][(row0 + 32) * 72 + c8] = kr1;
                *(uint4*)&Vs[cur ^ 1][row0 * 72 + c8] = vr0;
                *(uint4*)&Vs[cur ^ 1][(row0 + 32) * 72 + c8] = vr1;
            }
            __syncthreads();             // single barrier per iteration
        }
        // epilogue: O^T C-layout -> o[qrow][d]
        float rcp = 1.0f / l_r;
        const size_t orow = (size_t)(rowbase + qt * 64 + w * 16 + lrow) * DIM + h * 64;
        #pragma unroll
        for (int ct = 0; ct < 4; ++ct) {
            union { uint2 u; __bf16 h4[4]; } pk;
            #pragma unroll
            for (int r = 0; r < 4; ++r) pk.h4[r] = (__bf16)(oacc[ct][r] * rcp);
            *(uint2*)(o + orow + ct * 16 + lq * 4) = pk.u;
        }
    }
}

extern "C" void kernel_launch(void* const* d_in, const int* in_sizes, int n_in,
                              void* d_out, int out_size, void* d_ws, size_t ws_size,
                              hipStream_t stream) {
    const float* tokens = (const float*)d_in[0];
    const float* gamma  = (const float*)d_in[1];
    const float* wq = (const float*)d_in[2];
    const float* wk = (const float*)d_in[3];
    const float* wv = (const float*)d_in[4];
    const float* wo = (const float*)d_in[5];

    __bf16* ws  = (__bf16*)d_ws;
    __bf16* x   = ws;                           // 4096*1024
    __bf16* qb  = x   + (size_t)4096 * 1024;
    __bf16* kb  = qb  + (size_t)4096 * 1024;
    __bf16* vtb = kb  + (size_t)4096 * 1024;    // V^T: 1024 x 4096
    __bf16* ao  = x;                            // alias: attn out reuses x's buffer
    __bf16* wob = qb;                           // alias: qb dead after attn
    float*  out = (float*)d_out;

    // bf16 Q/K/V weights stashed in d_out (consumed by qkv before wo overwrites);
    // work-queue counters at d_out+8MB.
    __bf16* wqb = (__bf16*)d_out;
    __bf16* wkb = wqb + (size_t)1024 * 1024;
    __bf16* wvb = wkb + (size_t)1024 * 1024;
    int* counters = (int*)((char*)d_out + (size_t)8 * 1024 * 1024);

    cvt_kernel<<<1024, 256, 0, stream>>>(wq, wqb);
    cvt_kernel<<<1024, 256, 0, stream>>>(wk, wkb);
    cvt_kernel<<<1024, 256, 0, stream>>>(wv, wvb);

    rmsnorm_kernel<<<4096, 256, 0, stream>>>(tokens, gamma, x);

    qkv_kernel<<<dim3(32, 16, 3), 256, 0, stream>>>(x, wqb, wkb, wvb, qb, kb, vtb);

    rope_kernel<<<8192, 256, 0, stream>>>(qb);
    rope_kernel<<<8192, 256, 0, stream>>>(kb);

    init_kernel<<<1, 8, 0, stream>>>(counters);

    attn_kernel<<<512, 256, 0, stream>>>(qb, kb, vtb, ao, counters);

    cvt_kernel<<<1024, 256, 0, stream>>>(wo, wob);   // qb region is dead now

    wo_kernel<<<dim3(32, 16), 256, 0, stream>>>(ao, wob, out);
}